// Round 8
// baseline (161.070 us; speedup 1.0000x reference)
//
#include <hip/hip_runtime.h>

// QuantumSpectralConv: x[4,128,128,64] f32, W[16,16,64,64,4] re/im planes.
//   x_ft = DFT_{H,W}(x) truncated to 16x16 modes
//   om[b,k,m,o] = sum_{n,c} x_ft[b,k,n,c] * (sum_s W[m,n,c,o,s]) / 2
//   out = Re(iDFT zero-padded)  -> [4,128,128,64] f32
//
// 4-kernel pipeline. R6: twiddles as register rotations (no LDS chain).
// R7: k_gemm2 was LDS-pipe-bound (narrow b64 reads, 2-way bank aliasing,
// 4.19M conflict cycles). Now: lane owns 2 rows x 2 o's; B read as b128
// with 2 wave-addresses on disjoint bank groups (conflict-free); K split
// across the 8 waves, partials reduced through the retired Bs buffer.

static constexpr int BATCH = 4;
static constexpr float STEP_C = 0.9987954562051724f;   // cos(2*pi/128)
static constexpr float STEP_S = 0.04906767432741801f;  // sin(2*pi/128)

// float offsets into workspace
static constexpr size_t TMP_OFF = 0;          // tmp1: 524288 complex (4.2MB)
static constexpr size_t XFT_OFF = 1048576;    // 65536 complex (0.5MB)
static constexpr size_t OMT_OFF = 1179648;    // 65536 complex (0.5MB)

__device__ __forceinline__ float2 cmulp(float2 a, float2 b) {  // a*b (+i)
    return make_float2(a.x * b.x - a.y * b.y, a.x * b.y + a.y * b.x);
}

// DFT over W: tmp1[b,h,n,c] = sum_w x[b,h,w,c] * e^{-2pi i n w/128}, n<16
// block per (b,h) = 512 blocks. Thread: one n (tid>>4), 4 c's (tid&15).
__global__ __launch_bounds__(256) void k_dft_w(const float* __restrict__ x,
                                               float2* __restrict__ tmp1) {
    __shared__ float4 xs[2048];                       // [128 w][16 c4] = 32KB
    const int bid = blockIdx.x;                       // b*128 + h
    const float4* x4 = reinterpret_cast<const float4*>(x) + (size_t)bid * 2048;
    #pragma unroll
    for (int i = 0; i < 8; ++i) xs[threadIdx.x + 256 * i] = x4[threadIdx.x + 256 * i];
    const int n  = threadIdx.x >> 4;
    const int c4 = threadIdx.x & 15;
    float rs, rc;                                     // rot = e^{+2pi i n/128}
    sincosf(6.283185307179586f * (float)n * 0.0078125f, &rs, &rc);
    const float2 rot = make_float2(rc, rs);
    __syncthreads();
    float4 ar = make_float4(0.f, 0.f, 0.f, 0.f);
    float4 ai = make_float4(0.f, 0.f, 0.f, 0.f);
    float2 tw = make_float2(1.f, 0.f);                // e^{+2pi i n w/128}
    #pragma unroll 8
    for (int w = 0; w < 128; ++w) {
        const float4 v = xs[w * 16 + c4];
        ar.x += v.x * tw.x; ai.x -= v.x * tw.y;
        ar.y += v.y * tw.x; ai.y -= v.y * tw.y;
        ar.z += v.z * tw.x; ai.z -= v.z * tw.y;
        ar.w += v.w * tw.x; ai.w -= v.w * tw.y;
        tw = cmulp(tw, rot);
    }
    float4* o = reinterpret_cast<float4*>(tmp1 + ((size_t)bid * 16 + n) * 64 + c4 * 4);
    o[0] = make_float4(ar.x, ai.x, ar.y, ai.y);
    o[1] = make_float4(ar.z, ai.z, ar.w, ai.w);
}

// DFT over H: xft[(b*16+k)*1024+n*64+c] = sum_h tmp1[b,h,n,c] e^{-2pi i k h/128}
// grid 512 = (b 4, k 16, nh 8); thread: (hs = tid>>7) h-half, ol = tid&127.
__global__ __launch_bounds__(256) void k_dft_h(const float2* __restrict__ tmp1,
                                               float2* __restrict__ xft) {
    __shared__ float2 red[128];
    const int bid = blockIdx.x;
    const int nh = bid & 7;
    const int k  = (bid >> 3) & 15;
    const int b  = bid >> 7;
    const int ol = threadIdx.x & 127;
    const int hs = threadIdx.x >> 7;
    const int c  = ol & 63;
    const int n  = nh * 2 + (ol >> 6);
    float rs, rc;                                     // rot = e^{+2pi i k/128}
    sincosf(6.283185307179586f * (float)k * 0.0078125f, &rs, &rc);
    const float2 rot = make_float2(rc, rs);
    // start angle: 2pi*k*(hs*64)/128 = pi*k*hs -> (+-1, 0)
    float2 tw = make_float2((hs && (k & 1)) ? -1.f : 1.f, 0.f);
    const float2* src = tmp1 + (size_t)b * 131072 + n * 64 + c + (size_t)hs * 65536;
    float2 acc = make_float2(0.f, 0.f);
    #pragma unroll 8
    for (int j = 0; j < 64; ++j) {
        const float2 a = src[(size_t)j * 1024];
        acc.x += a.x * tw.x + a.y * tw.y;             // conj twiddle: (c-is)
        acc.y += a.y * tw.x - a.x * tw.y;
        tw = cmulp(tw, rot);
    }
    if (hs) red[ol] = acc;
    __syncthreads();
    if (!hs) {
        const float2 r = red[ol];
        acc.x += r.x; acc.y += r.y;
        xft[(size_t)(b * 16 + k) * 1024 + n * 64 + c] = acc;
    }
}

// Complex GEMM, fused Schmidt fold. grid 256 = (m 16, oq 16), 512 threads.
//   Bs[kk=(n,c)][o4] = sum_s W/2 (32KB, staged once, coalesced).
//   Wave ks = tid>>6 owns a 128-complex K-chunk. Lane: rows (r2, r2+32),
//   o-pair oh -> B via ds_read_b128, 2 wave-addresses, disjoint banks.
//   Partials (8 per output) reduced through Bs after compute.
//   Writes omT[b][m][o][k] (k innermost -- the layout k_idft consumes).
__global__ __launch_bounds__(512) void k_gemm2(const float2* __restrict__ xft,
                                               const float* __restrict__ wr,
                                               const float* __restrict__ wi,
                                               float2* __restrict__ omT) {
    __shared__ float2 Bs[4096];                       // [kk 1024][o 4] 32KB
    const int oq = blockIdx.x & 15;
    const int m  = blockIdx.x >> 4;
    #pragma unroll
    for (int i = 0; i < 8; ++i) {                     // stage B, sum over s
        const int idx = threadIdx.x + 512 * i;        // kk*4 + oo
        const int kk = idx >> 2, oo = idx & 3;
        const size_t wb = ((size_t)(m * 1024 + kk) * 64 + oq * 4 + oo) * 4;
        const float4 r4 = *reinterpret_cast<const float4*>(wr + wb);
        const float4 i4 = *reinterpret_cast<const float4*>(wi + wb);
        Bs[idx] = make_float2((r4.x + r4.y + r4.z + r4.w) * 0.5f,
                              (i4.x + i4.y + i4.z + i4.w) * 0.5f);
    }
    __syncthreads();
    const int ks = threadIdx.x >> 6;                  // wave -> K-chunk (128 cplx)
    const int l  = threadIdx.x & 63;
    const int r2 = l & 31;                            // rows r2, r2+32
    const int oh = l >> 5;                            // o-subpair 0/1
    const float4* xa = reinterpret_cast<const float4*>(xft + (size_t)r2 * 1024 + ks * 128);
    const float4* xb = reinterpret_cast<const float4*>(xft + (size_t)(r2 + 32) * 1024 + ks * 128);
    float2 acc00 = {}, acc01 = {}, acc10 = {}, acc11 = {};
    #pragma unroll 8
    for (int k2 = 0; k2 < 64; ++k2) {                 // 2 complex K per iter
        const float4 a0 = xa[k2];
        const float4 a1 = xb[k2];
        const int base = (ks * 128 + 2 * k2) * 4 + oh * 2;
        const float4 b0 = *reinterpret_cast<const float4*>(&Bs[base]);      // kk
        const float4 b1 = *reinterpret_cast<const float4*>(&Bs[base + 4]);  // kk+1
        acc00.x += a0.x * b0.x - a0.y * b0.y + a0.z * b1.x - a0.w * b1.y;
        acc00.y += a0.x * b0.y + a0.y * b0.x + a0.z * b1.y + a0.w * b1.x;
        acc01.x += a0.x * b0.z - a0.y * b0.w + a0.z * b1.z - a0.w * b1.w;
        acc01.y += a0.x * b0.w + a0.y * b0.z + a0.z * b1.w + a0.w * b1.z;
        acc10.x += a1.x * b0.x - a1.y * b0.y + a1.z * b1.x - a1.w * b1.y;
        acc10.y += a1.x * b0.y + a1.y * b0.x + a1.z * b1.y + a1.w * b1.x;
        acc11.x += a1.x * b0.z - a1.y * b0.w + a1.z * b1.z - a1.w * b1.w;
        acc11.y += a1.x * b0.w + a1.y * b0.z + a1.z * b1.w + a1.w * b1.z;
    }
    __syncthreads();                                  // Bs retired -> reduce buf
    Bs[ks * 256 + r2 * 4 + oh * 2]            = acc00;
    Bs[ks * 256 + r2 * 4 + oh * 2 + 1]        = acc01;
    Bs[ks * 256 + (r2 + 32) * 4 + oh * 2]     = acc10;
    Bs[ks * 256 + (r2 + 32) * 4 + oh * 2 + 1] = acc11;
    __syncthreads();
    if (threadIdx.x < 256) {                          // r = tid>>2, osub = tid&3
        const int r = threadIdx.x >> 2, osub = threadIdx.x & 3;
        float2 s = make_float2(0.f, 0.f);
        #pragma unroll
        for (int q = 0; q < 8; ++q) {
            const float2 v = Bs[q * 256 + threadIdx.x];
            s.x += v.x; s.y += v.y;
        }
        const int b = r >> 4, k = r & 15;
        omT[(((size_t)b * 16 + m) * 64 + oq * 4 + osub) * 16 + k] = s;
    }
}

// Fused inverse: block = (b,h) = 512 blocks.
//   u_s[m][o] = sum_k omT[b][m][o][k] e^{+2pi i k h/128}   (phase 1, LDS)
//   out[b,h,w,o] = (1/16384) * sum_m Re(u_s[m][o] e^{+2pi i m w/128})
// All twiddles register-rotated; u loaded to registers ONCE for phase 2.
__global__ __launch_bounds__(256) void k_idft(const float2* __restrict__ omT,
                                              float* __restrict__ out) {
    __shared__ float2 u_s[1024];                      // [m16][o64] 8KB
    const int bid = blockIdx.x;                       // b*128 + h
    const int h = bid & 127, b = bid >> 7;
    float hs_, hc_;                                   // rot_k = e^{+2pi i h/128}
    sincosf(6.283185307179586f * (float)h * 0.0078125f, &hs_, &hc_);
    const float2 rotk = make_float2(hc_, hs_);
    #pragma unroll
    for (int i = 0; i < 4; ++i) {                     // phase 1: 4 u per thread
        const int e = threadIdx.x + 256 * i;          // m*64 + o
        const float4* src = reinterpret_cast<const float4*>(
            omT + (((size_t)b * 16 + (e >> 6)) * 64 + (e & 63)) * 16);
        float re = 0.f, im = 0.f;
        float2 tw = make_float2(1.f, 0.f);            // e^{+2pi i k h/128}
        #pragma unroll
        for (int k8 = 0; k8 < 8; ++k8) {
            const float4 q = src[k8];                 // k = 2k8, 2k8+1
            re += q.x * tw.x - q.y * tw.y; im += q.x * tw.y + q.y * tw.x;
            tw = cmulp(tw, rotk);
            re += q.z * tw.x - q.w * tw.y; im += q.z * tw.y + q.w * tw.x;
            tw = cmulp(tw, rotk);
        }
        u_s[e] = make_float2(re, im);
    }
    __syncthreads();
    const int o4 = threadIdx.x & 15;                  // 4 o's
    const int wg = threadIdx.x >> 4;                  // 8 w's
    float4 va[16], vb[16];                            // u strip in registers
    #pragma unroll
    for (int mm = 0; mm < 16; ++mm) {
        const float4* up = reinterpret_cast<const float4*>(&u_s[mm * 64 + o4 * 4]);
        va[mm] = up[0];                               // complex o4*4+0, +1
        vb[mm] = up[1];                               // complex o4*4+2, +3
    }
    float ws_, wc_;                                   // rot_m = e^{+2pi i w/128}
    sincosf(6.283185307179586f * (float)(wg * 8) * 0.0078125f, &ws_, &wc_);
    float2 rotm = make_float2(wc_, ws_);
    const float2 step = make_float2(STEP_C, STEP_S);  // advance w by 1
    const float inv = 1.0f / 16384.0f;
    #pragma unroll
    for (int i = 0; i < 8; ++i) {
        const int w = wg * 8 + i;
        float4 acc = make_float4(0.f, 0.f, 0.f, 0.f);
        float2 tw = make_float2(1.f, 0.f);            // e^{+2pi i m w/128}
        #pragma unroll
        for (int mm = 0; mm < 16; ++mm) {
            acc.x += va[mm].x * tw.x - va[mm].y * tw.y;
            acc.y += va[mm].z * tw.x - va[mm].w * tw.y;
            acc.z += vb[mm].x * tw.x - vb[mm].y * tw.y;
            acc.w += vb[mm].z * tw.x - vb[mm].w * tw.y;
            tw = cmulp(tw, rotm);
        }
        acc.x *= inv; acc.y *= inv; acc.z *= inv; acc.w *= inv;
        *reinterpret_cast<float4*>(out + ((size_t)bid * 128 + w) * 64 + o4 * 4) = acc;
        rotm = cmulp(rotm, step);
    }
}

extern "C" void kernel_launch(void* const* d_in, const int* in_sizes, int n_in,
                              void* d_out, int out_size, void* d_ws, size_t ws_size,
                              hipStream_t stream) {
    const float* x  = (const float*)d_in[0];
    const float* wr = (const float*)d_in[1];
    const float* wi = (const float*)d_in[2];
    float* out = (float*)d_out;
    float* ws  = (float*)d_ws;

    float2* tmp1 = (float2*)(ws + TMP_OFF);
    float2* xft  = (float2*)(ws + XFT_OFF);
    float2* omT  = (float2*)(ws + OMT_OFF);

    k_dft_w<<<BATCH * 128, 256, 0, stream>>>(x, tmp1);
    k_dft_h<<<512, 256, 0, stream>>>(tmp1, xft);
    k_gemm2<<<256, 512, 0, stream>>>(xft, wr, wi, omT);
    k_idft <<<BATCH * 128, 256, 0, stream>>>(omT, out);
}